// Round 5
// baseline (172.391 us; speedup 1.0000x reference)
//
#include <hip/hip_runtime.h>

#define ROWS 1024
#define COLS 1024
#define NN (ROWS*COLS)

#define TILE_H 32
#define TILE_W 64
#define HALO   8
#define RH     48              // TILE_H + 2*HALO
#define RW     80              // TILE_W + 2*HALO
#define RC     (RH*RW)         // 3840 cells
#define SPR    (RW/4)          // 20 strips per row
#define NSTRIP (RC/4)          // 960 strips
#define NT     320             // threads (5 waves)
#define SPT    3               // strips per thread

static constexpr float RHOG    = 1000.0f * 9.81f;
static constexpr float INV_SEC = 1.0f / 31556926.0f;
static constexpr float FLOWC   = 0.0405f;

__device__ __forceinline__ float4 gld4(const float* __restrict__ p, int g, bool in) {
    if (in) return *reinterpret_cast<const float4*>(p + g);
    return make_float4(0.f, 0.f, 0.f, 0.f);
}

// ---- phi + inv_total ------------------------------------------------------
__global__ __launch_bounds__(256) void k_phi_inv(
        const float* __restrict__ bed, const float* __restrict__ pw,
        const int* __restrict__ status,
        float* __restrict__ phi, float* __restrict__ inv) {
    int i = blockIdx.x * 256 + threadIdx.x;
    int r = i >> 10, c = i & (COLS - 1);
    float p = RHOG * bed[i] + pw[i];
    float t = 0.f;
    if (c > 0)        t += fmaxf(p - (RHOG * bed[i - 1]    + pw[i - 1]),    0.f);
    if (c < COLS - 1) t += fmaxf(p - (RHOG * bed[i + 1]    + pw[i + 1]),    0.f);
    if (r > 0)        t += fmaxf(p - (RHOG * bed[i - COLS] + pw[i - COLS]), 0.f);
    if (r < ROWS - 1) t += fmaxf(p - (RHOG * bed[i + COLS] + pw[i + COLS]), 0.f);
    phi[i] = p;
    inv[i] = (status[i] == 0 && t > 0.f) ? (1.f / t) : 0.f;
}

// ---- per-cell incoming weights (W,E,N,S) + runoff, once -------------------
__global__ __launch_bounds__(256) void k_wgt(
        const float* __restrict__ phi, const float* __restrict__ inv,
        const float* __restrict__ melt, const float* __restrict__ area,
        float4* __restrict__ w, float* __restrict__ runoff) {
    int t = blockIdx.x * 256 + threadIdx.x;    // one thread per 4-cell strip
    int i = t * 4;
    int r = i >> 10, c = i & (COLS - 1);
    float4 pc = *reinterpret_cast<const float4*>(phi + i);
    float4 ic = *reinterpret_cast<const float4*>(inv + i);
    bool hn = (r > 0), hs = (r < ROWS - 1);
    float4 z = make_float4(0.f, 0.f, 0.f, 0.f);
    float4 pn = hn ? *reinterpret_cast<const float4*>(phi + i - COLS) : z;
    float4 vn = hn ? *reinterpret_cast<const float4*>(inv + i - COLS) : z;
    float4 ps = hs ? *reinterpret_cast<const float4*>(phi + i + COLS) : z;
    float4 vs = hs ? *reinterpret_cast<const float4*>(inv + i + COLS) : z;
    float pw_ = (c > 0) ? phi[i - 1] : 0.f, iw_ = (c > 0) ? inv[i - 1] : 0.f;
    float pe_ = (c < COLS - 4) ? phi[i + 4] : 0.f, ie_ = (c < COLS - 4) ? inv[i + 4] : 0.f;
    // masked inv (=0) zeroes out-of-grid weights automatically
    w[i + 0] = make_float4(fmaxf(pw_  - pc.x, 0.f) * iw_,
                           fmaxf(pc.y - pc.x, 0.f) * ic.y,
                           fmaxf(pn.x - pc.x, 0.f) * vn.x,
                           fmaxf(ps.x - pc.x, 0.f) * vs.x);
    w[i + 1] = make_float4(fmaxf(pc.x - pc.y, 0.f) * ic.x,
                           fmaxf(pc.z - pc.y, 0.f) * ic.z,
                           fmaxf(pn.y - pc.y, 0.f) * vn.y,
                           fmaxf(ps.y - pc.y, 0.f) * vs.y);
    w[i + 2] = make_float4(fmaxf(pc.y - pc.z, 0.f) * ic.y,
                           fmaxf(pc.w - pc.z, 0.f) * ic.w,
                           fmaxf(pn.z - pc.z, 0.f) * vn.z,
                           fmaxf(ps.z - pc.z, 0.f) * vs.z);
    w[i + 3] = make_float4(fmaxf(pc.z - pc.w, 0.f) * ic.z,
                           fmaxf(pe_  - pc.w, 0.f) * ie_,
                           fmaxf(pn.w - pc.w, 0.f) * vn.w,
                           fmaxf(ps.w - pc.w, 0.f) * vs.w);
    float4 m4 = *reinterpret_cast<const float4*>(melt + i);
    float4 a4 = *reinterpret_cast<const float4*>(area + i);
    *reinterpret_cast<float4*>(runoff + i) =
        make_float4(m4.x * a4.x * INV_SEC, m4.y * a4.y * INV_SEC,
                    m4.z * a4.z * INV_SEC, m4.w * a4.w * INV_SEC);
}

// ---- fused 8-step halo-tiled Jacobi ---------------------------------------
// Weights loaded (not recomputed). Own strip in registers; W/E edges via
// conflict-free lane-stride-1 planes; N/S via b128 LDS. Cell at region-
// border-distance d holds q^min(s,d); frozen-cell reads are don't-care.
template <bool FIRST, bool FINAL>
__global__ __launch_bounds__(NT) void k_fused(
        const float4* __restrict__ w_g, const float* __restrict__ run_g,
        const float* __restrict__ qin, float* __restrict__ qout,
        const float* __restrict__ cond, const int* __restrict__ status) {
    __shared__ float ldsq[2][RC];            // 30720 B
    __shared__ float plane[2][2][NSTRIP];    // 15360 B
    const int tid = threadIdx.x;
    const int r0 = (int)blockIdx.y * TILE_H - HALO;
    const int c0 = (int)blockIdx.x * TILE_W - HALO;

    int xC[SPT], xN[SPT], xS[SPT], gg[SPT], sidA[SPT], sidW[SPT], sidE[SPT];
    bool inA[SPT], inter[SPT];
    float4 ro[SPT], oq[SPT];
    float4 wc0[SPT], wc1[SPT], wc2[SPT], wc3[SPT];   // per-cell (W,E,N,S)
    int4 dd[SPT];

#pragma unroll
    for (int j = 0; j < SPT; ++j) {
        int sid = tid + j * NT;
        sidA[j] = sid;
        sidW[j] = (sid > 0) ? sid - 1 : 0;
        sidE[j] = (sid < NSTRIP - 1) ? sid + 1 : NSTRIP - 1;
        int sr = sid / SPR, sc = sid - sr * SPR;
        int iC = sr * RW + 4 * sc;
        xC[j] = iC;
        xN[j] = (sr > 0)      ? iC - RW : iC;
        xS[j] = (sr < RH - 1) ? iC + RW : iC;
        int gr = r0 + sr, gc = c0 + 4 * sc;
        inA[j] = (gr >= 0) & (gr < ROWS) & (gc >= 0) & (gc < COLS);
        inter[j] = (sr >= HALO) & (sr < RH - HALO) & (sc >= HALO / 4) & (sc < SPR - HALO / 4);
        gg[j] = gr * COLS + gc;
        int drow = min(sr, RH - 1 - sr);
        int cc = 4 * sc;
        dd[j].x = min(drow, min(cc,     RW - 1 - cc));
        dd[j].y = min(drow, min(cc + 1, RW - 2 - cc));
        dd[j].z = min(drow, min(cc + 2, RW - 3 - cc));
        dd[j].w = min(drow, min(cc + 3, RW - 4 - cc));
    }

    // stage: weights + runoff + q0 straight to registers; q0 -> LDS/planes
#pragma unroll
    for (int j = 0; j < SPT; ++j) {
        const float* wb = (const float*)(w_g + gg[j]);
        bool in = inA[j];
        wc0[j] = gld4(wb, 0,  in);
        wc1[j] = gld4(wb, 4,  in);
        wc2[j] = gld4(wb, 8,  in);
        wc3[j] = gld4(wb, 12, in);
        ro[j]  = gld4(run_g, gg[j], in);
        float4 q0 = FIRST ? ro[j] : gld4(qin, gg[j], in);
        oq[j] = q0;
        *reinterpret_cast<float4*>(&ldsq[0][xC[j]]) = q0;
        plane[0][0][sidA[j]] = q0.x;
        plane[0][1][sidA[j]] = q0.w;
    }
    __syncthreads();

    // 8 Jacobi steps, LDS ping-pong
    for (int s = 0; s < HALO; ++s) {
        const float* __restrict__ src = ldsq[s & 1];
        float* __restrict__ dst = ldsq[(s + 1) & 1];
        const float* __restrict__ pL = plane[s & 1][0];
        const float* __restrict__ pR = plane[s & 1][1];
        float* __restrict__ qL = plane[(s + 1) & 1][0];
        float* __restrict__ qR = plane[(s + 1) & 1][1];
#pragma unroll
        for (int j = 0; j < SPT; ++j) {
            float4 cv = oq[j];
            float wv = pR[sidW[j]];          // right edge of left strip
            float ev = pL[sidE[j]];          // left edge of right strip
            float4 nv = *reinterpret_cast<const float4*>(&src[xN[j]]);
            float4 sv = *reinterpret_cast<const float4*>(&src[xS[j]]);
            float4 acc;
            acc.x = fmaf(wc0[j].x, wv,   ro[j].x);
            acc.y = fmaf(wc1[j].x, cv.x, ro[j].y);
            acc.z = fmaf(wc2[j].x, cv.y, ro[j].z);
            acc.w = fmaf(wc3[j].x, cv.z, ro[j].w);
            acc.x = fmaf(wc0[j].y, cv.y, acc.x);
            acc.y = fmaf(wc1[j].y, cv.z, acc.y);
            acc.z = fmaf(wc2[j].y, cv.w, acc.z);
            acc.w = fmaf(wc3[j].y, ev,   acc.w);
            acc.x = fmaf(wc0[j].z, nv.x, acc.x);
            acc.y = fmaf(wc1[j].z, nv.y, acc.y);
            acc.z = fmaf(wc2[j].z, nv.z, acc.z);
            acc.w = fmaf(wc3[j].z, nv.w, acc.w);
            acc.x = fmaf(wc0[j].w, sv.x, acc.x);
            acc.y = fmaf(wc1[j].w, sv.y, acc.y);
            acc.z = fmaf(wc2[j].w, sv.z, acc.z);
            acc.w = fmaf(wc3[j].w, sv.w, acc.w);
            float4 o;
            o.x = (s < dd[j].x) ? acc.x : cv.x;
            o.y = (s < dd[j].y) ? acc.y : cv.y;
            o.z = (s < dd[j].z) ? acc.z : cv.z;
            o.w = (s < dd[j].w) ? acc.w : cv.w;
            oq[j] = o;
            *reinterpret_cast<float4*>(&dst[xC[j]]) = o;
            qL[sidA[j]] = o.x;
            qR[sidA[j]] = o.w;
        }
        __syncthreads();
    }

    // write 32x64 interior (q^8 lives in oq registers)
#pragma unroll
    for (int j = 0; j < SPT; ++j) {
        if (inter[j]) {
            int g = gg[j];
            float4 q = oq[j];
            if (FINAL) {
                float4 c4 = *reinterpret_cast<const float4*>(cond + g);
                int4 st   = *reinterpret_cast<const int4*>(status + g);
                float4 o;
                float t;
                t = q.x * FLOWC * (c4.x * sqrtf(sqrtf(c4.x))); o.x = (st.x == 0) ? t * t : 0.f;
                t = q.y * FLOWC * (c4.y * sqrtf(sqrtf(c4.y))); o.y = (st.y == 0) ? t * t : 0.f;
                t = q.z * FLOWC * (c4.z * sqrtf(sqrtf(c4.z))); o.z = (st.z == 0) ? t * t : 0.f;
                t = q.w * FLOWC * (c4.w * sqrtf(sqrtf(c4.w))); o.w = (st.w == 0) ? t * t : 0.f;
                *reinterpret_cast<float4*>(qout + g) = o;
            } else {
                *reinterpret_cast<float4*>(qout + g) = q;
            }
        }
    }
}

extern "C" void kernel_launch(void* const* d_in, const int* in_sizes, int n_in,
                              void* d_out, int out_size, void* d_ws, size_t ws_size,
                              hipStream_t stream) {
    const float* melt   = (const float*)d_in[0];
    const float* bed    = (const float*)d_in[1];
    const float* pw     = (const float*)d_in[2];
    const float* area   = (const float*)d_in[3];
    const float* cond   = (const float*)d_in[4];
    const int*   status = (const int*)d_in[5];
    float* out = (float*)d_out;

    char* ws = (char*)d_ws;
    float*  phi    = (float*)(ws);                    //  4 MB
    float*  inv    = (float*)(ws + 4ull  * NN);       //  4 MB
    float4* w      = (float4*)(ws + 8ull  * NN);      // 16 MB
    float*  runoff = (float*)(ws + 24ull * NN);       //  4 MB
    float*  qA     = (float*)(ws + 28ull * NN);       //  4 MB
    float*  qB     = (float*)(ws + 32ull * NN);       //  4 MB (36 MB total)

    k_phi_inv<<<dim3(NN / 256), dim3(256), 0, stream>>>(bed, pw, status, phi, inv);
    k_wgt<<<dim3(NN / 1024), dim3(256), 0, stream>>>(phi, inv, melt, area, w, runoff);

    dim3 grid(COLS / TILE_W, ROWS / TILE_H), block(NT);
    k_fused<true,  false><<<grid, block, 0, stream>>>(w, runoff, runoff, qA, nullptr, nullptr);
    k_fused<false, false><<<grid, block, 0, stream>>>(w, runoff, qA, qB, nullptr, nullptr);
    k_fused<false, false><<<grid, block, 0, stream>>>(w, runoff, qB, qA, nullptr, nullptr);
    k_fused<false, true ><<<grid, block, 0, stream>>>(w, runoff, qA, out, cond, status);
}

// Round 6
// 141.288 us; speedup vs baseline: 1.2201x; 1.2201x over previous
//
#include <hip/hip_runtime.h>

#define ROWS 1024
#define COLS 1024
#define NN (ROWS*COLS)

#define TILE_H 32
#define TILE_W 64
#define HALO   8
#define RH     48              // TILE_H + 2*HALO
#define RW     80              // TILE_W + 2*HALO
#define RC     (RH*RW)         // 3840 cells
#define SPR    (RW/4)          // 20 float4-strips per region row
#define NSTRIP (RC/4)          // 960
#define NT     256
#define BR     (RH/4)          // 12 block-rows of 4x4 cells
#define BC     (RW/4)          // 20 block-cols
#define NB4    (BR*BC)         // 240 active threads

static constexpr float RHOG    = 1000.0f * 9.81f;
static constexpr float INV_SEC = 1.0f / 31556926.0f;
static constexpr float FLOWC   = 0.0405f;

__device__ __forceinline__ float4 gld4(const float* __restrict__ p, int g, bool in) {
    if (in) return *reinterpret_cast<const float4*>(p + g);
    return make_float4(0.f, 0.f, 0.f, 0.f);
}

// ---- prologue: phi, inv_total, runoff -------------------------------------
__global__ __launch_bounds__(256) void k_pre(
        const float* __restrict__ bed, const float* __restrict__ pw,
        const int* __restrict__ status,
        const float* __restrict__ melt, const float* __restrict__ area,
        float* __restrict__ phi, float* __restrict__ inv,
        float* __restrict__ runoff) {
    int i = blockIdx.x * 256 + threadIdx.x;
    int r = i >> 10, c = i & (COLS - 1);
    float p = RHOG * bed[i] + pw[i];
    float t = 0.f;
    if (c > 0)        t += fmaxf(p - (RHOG * bed[i - 1]    + pw[i - 1]),    0.f);
    if (c < COLS - 1) t += fmaxf(p - (RHOG * bed[i + 1]    + pw[i + 1]),    0.f);
    if (r > 0)        t += fmaxf(p - (RHOG * bed[i - COLS] + pw[i - COLS]), 0.f);
    if (r < ROWS - 1) t += fmaxf(p - (RHOG * bed[i + COLS] + pw[i + COLS]), 0.f);
    phi[i]    = p;
    inv[i]    = (status[i] == 0 && t > 0.f) ? (1.f / t) : 0.f;
    runoff[i] = melt[i] * area[i] * INV_SEC;
}

// ---- fused 8-step halo-tiled Jacobi, 4x4 cells per thread -----------------
// Interior neighbors from registers; only 4x4-block edges go through LDS
// (contiguous float4 planes, double-buffered). Weights recomputed once from
// LDS-staged phi/inv (8 B/cell traffic, cheaper than a 16 B/cell w-table: R5).
// Cell at region-border-distance d holds q^min(s,d); border blocks freeze via
// cndmask; interior (= output tile) blocks never freeze.
template <bool FIRST, bool FINAL>
__global__ __launch_bounds__(256) void k_fused(
        const float* __restrict__ phi_g, const float* __restrict__ inv_g,
        const float* __restrict__ run_g, const float* __restrict__ qin,
        float* __restrict__ qout,
        const float* __restrict__ cond, const int* __restrict__ status) {
    __shared__ float A[RC];                      // phi staging  (15360 B)
    __shared__ float Bv[RC];                     // inv staging  (15360 B)
    __shared__ float4 plT[2][NB4], plB[2][NB4];  // top/bottom row planes
    __shared__ float4 plL[2][NB4], plR[2][NB4];  // left/right col planes (30720 B)
    const int tid = threadIdx.x;
    const int r0 = (int)blockIdx.y * TILE_H - HALO;
    const int c0 = (int)blockIdx.x * TILE_W - HALO;

    // stage phi, inv (all 256 threads)
#pragma unroll
    for (int k = 0; k < 4; ++k) {
        int sidx = tid + k * NT;
        if (sidx < NSTRIP) {
            int sr = sidx / SPR, sc4 = (sidx - sr * SPR) * 4;
            int gr = r0 + sr, gc = c0 + sc4;
            bool in = (gr >= 0) & (gr < ROWS) & (gc >= 0) & (gc < COLS);
            int g = gr * COLS + gc;
            *reinterpret_cast<float4*>(&A[sr * RW + sc4])  = gld4(phi_g, g, in);
            *reinterpret_cast<float4*>(&Bv[sr * RW + sc4]) = gld4(inv_g, g, in);
        }
    }
    __syncthreads();

    const bool active = (tid < NB4);
    const int br = tid / BC, bc = tid - (tid / BC) * BC;
    const int rr0 = 4 * br, cc0 = 4 * bc;
    const bool inter = (br >= 2) & (br <= BR - 3) & (bc >= 2) & (bc <= BC - 3);

    float wW[4][4], wE[4][4], wN[4][4], wS[4][4];
    float q[4][4], ro[4][4];
    int dd[4][4];

    if (active) {
        // weights from LDS phi/inv; clamped edge reads yield weight 0
#pragma unroll
        for (int i = 0; i < 4; ++i) {
            int rr = rr0 + i;
            int x = rr * RW + cc0;
            float4 pc = *reinterpret_cast<const float4*>(&A[x]);
            float4 ic = *reinterpret_cast<const float4*>(&Bv[x]);
            int xu = (rr > 0)      ? x - RW : x;
            int xd = (rr < RH - 1) ? x + RW : x;
            float4 pu = *reinterpret_cast<const float4*>(&A[xu]);
            float4 iu = *reinterpret_cast<const float4*>(&Bv[xu]);
            float4 pd = *reinterpret_cast<const float4*>(&A[xd]);
            float4 id = *reinterpret_cast<const float4*>(&Bv[xd]);
            float pl = (cc0 > 0)      ? A[x - 1]  : pc.x;
            float il = (cc0 > 0)      ? Bv[x - 1] : 0.f;
            float pr = (cc0 < RW - 4) ? A[x + 4]  : pc.w;
            float ir = (cc0 < RW - 4) ? Bv[x + 4] : 0.f;
            wN[i][0] = fmaxf(pu.x - pc.x, 0.f) * iu.x;
            wN[i][1] = fmaxf(pu.y - pc.y, 0.f) * iu.y;
            wN[i][2] = fmaxf(pu.z - pc.z, 0.f) * iu.z;
            wN[i][3] = fmaxf(pu.w - pc.w, 0.f) * iu.w;
            wS[i][0] = fmaxf(pd.x - pc.x, 0.f) * id.x;
            wS[i][1] = fmaxf(pd.y - pc.y, 0.f) * id.y;
            wS[i][2] = fmaxf(pd.z - pc.z, 0.f) * id.z;
            wS[i][3] = fmaxf(pd.w - pc.w, 0.f) * id.w;
            wW[i][0] = fmaxf(pl   - pc.x, 0.f) * il;
            wW[i][1] = fmaxf(pc.x - pc.y, 0.f) * ic.x;
            wW[i][2] = fmaxf(pc.y - pc.z, 0.f) * ic.y;
            wW[i][3] = fmaxf(pc.z - pc.w, 0.f) * ic.z;
            wE[i][0] = fmaxf(pc.y - pc.x, 0.f) * ic.y;
            wE[i][1] = fmaxf(pc.z - pc.y, 0.f) * ic.z;
            wE[i][2] = fmaxf(pc.w - pc.z, 0.f) * ic.w;
            wE[i][3] = fmaxf(pr   - pc.w, 0.f) * ir;
        }
#pragma unroll
        for (int i = 0; i < 4; ++i)
#pragma unroll
            for (int j = 0; j < 4; ++j) {
                int rr = rr0 + i, cc = cc0 + j;
                dd[i][j] = min(min(rr, RH - 1 - rr), min(cc, RW - 1 - cc));
            }
        // runoff + q0 straight from global to registers
#pragma unroll
        for (int i = 0; i < 4; ++i) {
            int gr = r0 + rr0 + i, gc = c0 + cc0;
            bool in = (gr >= 0) & (gr < ROWS) & (gc >= 0) & (gc < COLS);
            int g = gr * COLS + gc;
            float4 r4 = gld4(run_g, g, in);
            ro[i][0] = r4.x; ro[i][1] = r4.y; ro[i][2] = r4.z; ro[i][3] = r4.w;
            float4 q4 = FIRST ? r4 : gld4(qin, g, in);
            q[i][0] = q4.x; q[i][1] = q4.y; q[i][2] = q4.z; q[i][3] = q4.w;
        }
        plT[0][tid] = make_float4(q[0][0], q[0][1], q[0][2], q[0][3]);
        plB[0][tid] = make_float4(q[3][0], q[3][1], q[3][2], q[3][3]);
        plL[0][tid] = make_float4(q[0][0], q[1][0], q[2][0], q[3][0]);
        plR[0][tid] = make_float4(q[0][3], q[1][3], q[2][3], q[3][3]);
    }
    __syncthreads();

    // 8 Jacobi steps; only block edges touch LDS
    for (int s = 0; s < HALO; ++s) {
        const int pp = s & 1, pn = pp ^ 1;
        if (active) {
            float4 up = plB[pp][(br > 0)      ? tid - BC : tid];
            float4 dn = plT[pp][(br < BR - 1) ? tid + BC : tid];
            float4 lf = plR[pp][(bc > 0)      ? tid - 1  : tid];
            float4 rt = plL[pp][(bc < BC - 1) ? tid + 1  : tid];
            float upv[4] = {up.x, up.y, up.z, up.w};
            float dnv[4] = {dn.x, dn.y, dn.z, dn.w};
            float lfv[4] = {lf.x, lf.y, lf.z, lf.w};
            float rtv[4] = {rt.x, rt.y, rt.z, rt.w};
            float nq[4][4];
#pragma unroll
            for (int i = 0; i < 4; ++i)
#pragma unroll
                for (int j = 0; j < 4; ++j) {
                    float uv = (i > 0) ? q[i - 1][j] : upv[j];
                    float dv = (i < 3) ? q[i + 1][j] : dnv[j];
                    float lv = (j > 0) ? q[i][j - 1] : lfv[i];
                    float rv = (j < 3) ? q[i][j + 1] : rtv[i];
                    float a = ro[i][j];
                    a = fmaf(wW[i][j], lv, a);
                    a = fmaf(wE[i][j], rv, a);
                    a = fmaf(wN[i][j], uv, a);
                    a = fmaf(wS[i][j], dv, a);
                    nq[i][j] = a;
                }
            if (!inter) {      // border blocks: freeze cells past their depth
#pragma unroll
                for (int i = 0; i < 4; ++i)
#pragma unroll
                    for (int j = 0; j < 4; ++j)
                        nq[i][j] = (s < dd[i][j]) ? nq[i][j] : q[i][j];
            }
#pragma unroll
            for (int i = 0; i < 4; ++i)
#pragma unroll
                for (int j = 0; j < 4; ++j) q[i][j] = nq[i][j];
            plT[pn][tid] = make_float4(q[0][0], q[0][1], q[0][2], q[0][3]);
            plB[pn][tid] = make_float4(q[3][0], q[3][1], q[3][2], q[3][3]);
            plL[pn][tid] = make_float4(q[0][0], q[1][0], q[2][0], q[3][0]);
            plR[pn][tid] = make_float4(q[0][3], q[1][3], q[2][3], q[3][3]);
        }
        __syncthreads();
    }

    // interior blocks == the 32x64 output tile exactly
    if (active && inter) {
#pragma unroll
        for (int i = 0; i < 4; ++i) {
            int g = (r0 + rr0 + i) * COLS + (c0 + cc0);
            if (FINAL) {
                float4 c4 = *reinterpret_cast<const float4*>(cond + g);
                int4 st   = *reinterpret_cast<const int4*>(status + g);
                float4 o;
                float t;
                t = q[i][0] * FLOWC * (c4.x * sqrtf(sqrtf(c4.x))); o.x = (st.x == 0) ? t * t : 0.f;
                t = q[i][1] * FLOWC * (c4.y * sqrtf(sqrtf(c4.y))); o.y = (st.y == 0) ? t * t : 0.f;
                t = q[i][2] * FLOWC * (c4.z * sqrtf(sqrtf(c4.z))); o.z = (st.z == 0) ? t * t : 0.f;
                t = q[i][3] * FLOWC * (c4.w * sqrtf(sqrtf(c4.w))); o.w = (st.w == 0) ? t * t : 0.f;
                *reinterpret_cast<float4*>(qout + g) = o;
            } else {
                *reinterpret_cast<float4*>(qout + g) =
                    make_float4(q[i][0], q[i][1], q[i][2], q[i][3]);
            }
        }
    }
}

extern "C" void kernel_launch(void* const* d_in, const int* in_sizes, int n_in,
                              void* d_out, int out_size, void* d_ws, size_t ws_size,
                              hipStream_t stream) {
    const float* melt   = (const float*)d_in[0];
    const float* bed    = (const float*)d_in[1];
    const float* pw     = (const float*)d_in[2];
    const float* area   = (const float*)d_in[3];
    const float* cond   = (const float*)d_in[4];
    const int*   status = (const int*)d_in[5];
    float* out = (float*)d_out;

    char* ws = (char*)d_ws;
    float* phi    = (float*)(ws);                 //  4 MB
    float* inv    = (float*)(ws + 4ull  * NN);    //  4 MB
    float* runoff = (float*)(ws + 8ull  * NN);    //  4 MB
    float* qA     = (float*)(ws + 12ull * NN);    //  4 MB
    float* qB     = (float*)(ws + 16ull * NN);    //  4 MB (20 MB total)

    k_pre<<<dim3(NN / 256), dim3(256), 0, stream>>>(bed, pw, status, melt, area,
                                                    phi, inv, runoff);

    dim3 grid(COLS / TILE_W, ROWS / TILE_H), block(NT);
    k_fused<true,  false><<<grid, block, 0, stream>>>(phi, inv, runoff, runoff, qA, nullptr, nullptr);
    k_fused<false, false><<<grid, block, 0, stream>>>(phi, inv, runoff, qA, qB, nullptr, nullptr);
    k_fused<false, false><<<grid, block, 0, stream>>>(phi, inv, runoff, qB, qA, nullptr, nullptr);
    k_fused<false, true ><<<grid, block, 0, stream>>>(phi, inv, runoff, qA, out, cond, status);
}